// Round 4
// baseline (11530.961 us; speedup 1.0000x reference)
//
#include <hip/hip_runtime.h>
#include <hip/hip_bf16.h>
#include <math.h>

typedef __hip_bfloat16 bf16;
__device__ __forceinline__ float b2f(bf16 v){ return __bfloat162float(v); }
__device__ __forceinline__ bf16  f2b(float v){ return __float2bfloat16(v); }

// storage-type helpers (fp32 bundles when ws allows, bf16 fallback)
__device__ __forceinline__ float ldst(const float* p, size_t i){ return p[i]; }
__device__ __forceinline__ float ldst(const bf16*  p, size_t i){ return b2f(p[i]); }
__device__ __forceinline__ void  stst(float* p, size_t i, float v){ p[i] = v; }
__device__ __forceinline__ void  stst(bf16*  p, size_t i, float v){ p[i] = f2b(v); }

#define BL 2048
#define BW 672            // bundle width: 384 + 288

// ---------- init: copy res_feature fp32 -> x ----------
__global__ void k_init(const float* __restrict__ rf, float* __restrict__ x) {
    int i = blockIdx.x * 256 + threadIdx.x;   // BL*128 = 262144
    x[i] = rf[i];
}

// ---------- projections + frame transform -> bundles ----------
template<typename ST>
__global__ __launch_bounds__(256, 4) void k_proj(
    const float* __restrict__ x,
    const float* __restrict__ Wq, const float* __restrict__ Wk, const float* __restrict__ Wv,
    const float* __restrict__ Wqp, const float* __restrict__ Wkp, const float* __restrict__ Wvp,
    const float* __restrict__ rot, const float* __restrict__ pos,
    ST* __restrict__ QB, ST* __restrict__ KB, ST* __restrict__ VB, int l)
{
    const size_t o384 = (size_t)l * 128 * 384, o288 = (size_t)l * 128 * 288;
    __shared__ float xr[128];
    __shared__ float ob[2016];
    __shared__ float Rm[9], tv[3];
    int row = blockIdx.x, tid = threadIdx.x;

    if (tid < 128)          xr[tid]       = x[(size_t)row * 128 + tid];
    else if (tid < 137)     Rm[tid - 128] = rot[(size_t)row * 9 + (tid - 128)];
    else if (tid < 140)     tv[tid - 137] = pos[(size_t)row * 3 + (tid - 137)];
    __syncthreads();

    for (int c = tid; c < 2016; c += 256) {
        const float* W; int col, wc; size_t wo;
        if (c < 1152) { int seg = c / 384; col = c - seg * 384; wc = 384; wo = o384;
                        W = (seg == 0) ? Wq : (seg == 1 ? Wk : Wv); }
        else          { int seg = (c - 1152) / 288; col = (c - 1152) - seg * 288; wc = 288; wo = o288;
                        W = (seg == 0) ? Wqp : (seg == 1 ? Wkp : Wvp); }
        float acc = 0.f;
        #pragma unroll 8
        for (int kk = 0; kk < 128; kk++) acc += xr[kk] * W[wo + (size_t)kk * wc + col];
        ob[c] = acc;
    }
    __syncthreads();

    // q/k/v into bundle slots [0,384)
    size_t rb = (size_t)row * BW;
    for (int c = tid; c < 384; c += 256) {
        stst(QB, rb + c, ob[c]);
        stst(KB, rb + c, ob[384 + c]);
        stst(VB, rb + c, ob[768 + c]);
    }
    // frame transform g = R*p + t into bundle slots [384, 672)
    for (int pt = tid; pt < 288; pt += 256) {
        int ty = pt / 96; int ip = pt - ty * 96; int base = 1152 + ty * 288 + ip * 3;
        float p0 = ob[base], p1 = ob[base + 1], p2 = ob[base + 2];
        float g0 = Rm[0] * p0 + Rm[1] * p1 + Rm[2] * p2 + tv[0];
        float g1 = Rm[3] * p0 + Rm[4] * p1 + Rm[5] * p2 + tv[1];
        float g2 = Rm[6] * p0 + Rm[7] * p1 + Rm[8] * p2 + tv[2];
        ST* dst = (ty == 0) ? QB : (ty == 1 ? KB : VB);
        stst(dst, rb + 384 + ip * 3 + 0, g0);
        stst(dst, rb + 384 + ip * 3 + 1, g1);
        stst(dst, rb + 384 + ip * 3 + 2, g2);
    }
}

// ---------- fused attention + Wo + LN1 + MLP + LN2 ----------
template<typename ST>
__global__ __launch_bounds__(256, 4) void k_attn(
    const ST* __restrict__ QB, const ST* __restrict__ KB, const ST* __restrict__ VB,
    const float* __restrict__ z, const float* __restrict__ Wpb, const float* __restrict__ coef,
    const float* __restrict__ rot, const float* __restrict__ pos,
    float* __restrict__ x,
    const float* __restrict__ Wo, const float* __restrict__ bo,
    const float* __restrict__ g1, const float* __restrict__ b1ln,
    const float* __restrict__ w1, const float* __restrict__ bb1,
    const float* __restrict__ w2, const float* __restrict__ bb2,
    const float* __restrict__ w3, const float* __restrict__ bb3,
    const float* __restrict__ g2, const float* __restrict__ b2ln, int l)
{
    const size_t oWpb = (size_t)l * 768, oCo = (size_t)l * 12;
    const size_t oWo = (size_t)l * 1824 * 128, oB = (size_t)l * 128, oM = (size_t)l * 128 * 128;

    __shared__ float al[12][256];   // alpha
    __shared__ float fr[1824];      // feat_all
    __shared__ float qi[672];       // q | qp_g bundle of row i
    __shared__ float aggr[288];
    __shared__ float wpb[768];
    __shared__ float chv[12], qp2s[12];
    __shared__ float Rm[9], tv[3];
    __shared__ float red[12][8];
    __shared__ float red2[4];
    __shared__ float pacc[256], shx[128];

    int tid = threadIdx.x;
    int bid = blockIdx.x;
    int b = bid & 7, i = bid >> 3;          // XCD swizzle: batch b pinned per XCD
    int row = b * 256 + i;

    // ---- staging ----
    for (int c = tid; c < 672; c += 256) qi[c] = ldst(QB, (size_t)row * BW + c);
    for (int c = tid; c < 768; c += 256) wpb[c] = Wpb[oWpb + c];
    if (tid < 12)                 chv[tid]     = -log1pf(expf(coef[oCo + tid])) * (1.f / 12.f);
    else if (tid >= 16 && tid < 25) Rm[tid-16] = rot[(size_t)row * 9 + (tid - 16)];
    else if (tid >= 25 && tid < 28) tv[tid-25] = pos[(size_t)row * 3 + (tid - 25)];
    __syncthreads();
    if (tid < 12) {
        float s = 0.f;
        #pragma unroll
        for (int m = 0; m < 24; m++) { float qv = qi[384 + tid * 24 + m]; s += qv * qv; }
        qp2s[tid] = s;
    }
    __syncthreads();

    // ---- logits for column j = tid ----
    const int j = tid;
    float lg[12];
    #pragma unroll
    for (int h = 0; h < 12; h++) lg[h] = 0.f;

    const float* zr = z + ((size_t)row * 256 + j) * 64;
    for (int d = 0; d < 64; d += 4) {
        float z0 = zr[d], z1 = zr[d+1], z2 = zr[d+2], z3 = zr[d+3];
        #pragma unroll
        for (int h = 0; h < 12; h++)
            lg[h] += z0 * wpb[d*12+h] + z1 * wpb[(d+1)*12+h]
                   + z2 * wpb[(d+2)*12+h] + z3 * wpb[(d+3)*12+h];
    }
    const ST* kb = KB + ((size_t)b * 256 + j) * BW;
    #pragma unroll
    for (int h = 0; h < 12; h++) {
        float nd = 0.f;
        #pragma unroll
        for (int d = 0; d < 32; d++) nd += qi[h * 32 + d] * ldst(kb, h * 32 + d);
        float qk = 0.f, kp2 = 0.f;
        #pragma unroll
        for (int m = 0; m < 24; m++) {
            float kv = ldst(kb, 384 + h * 24 + m);
            qk += qi[384 + h * 24 + m] * kv; kp2 += kv * kv;
        }
        float sp = chv[h] * (qp2s[h] + kp2 - 2.f * qk);
        lg[h] = (lg[h] + nd * 0.17677669529663687f + sp) * 0.5773502691896258f;
    }

    // ---- softmax over j (4 waves) ----
    int w = tid >> 6;
    #pragma unroll
    for (int h = 0; h < 12; h++) {
        float vv = lg[h];
        for (int off = 32; off; off >>= 1) vv = fmaxf(vv, __shfl_xor(vv, off, 64));
        if ((tid & 63) == 0) red[h][w] = vv;
    }
    __syncthreads();
    float mh[12];
    #pragma unroll
    for (int h = 0; h < 12; h++)
        mh[h] = fmaxf(fmaxf(red[h][0], red[h][1]), fmaxf(red[h][2], red[h][3]));
    #pragma unroll
    for (int h = 0; h < 12; h++) {
        float e = expf(lg[h] - mh[h]); lg[h] = e;
        float ss = e;
        for (int off = 32; off; off >>= 1) ss += __shfl_xor(ss, off, 64);
        if ((tid & 63) == 0) red[h][4 + w] = ss;
    }
    __syncthreads();
    #pragma unroll
    for (int h = 0; h < 12; h++) {
        float S = red[h][4] + red[h][5] + red[h][6] + red[h][7];
        al[h][j] = lg[h] / S;
    }
    __syncthreads();

    // ---- outputs: feat_node(384) | feat_pair(768) | aggr(288) ----
    for (int o = tid; o < 1440; o += 256) {
        float acc = 0.f;
        if (o < 384) {
            int h = o >> 5;
            const ST* vb = VB + (size_t)b * 256 * BW + o;
            #pragma unroll 4
            for (int jj = 0; jj < 256; jj++) acc += al[h][jj] * ldst(vb, (size_t)jj * BW);
            fr[o] = acc;
        } else if (o < 1152) {
            int oo = o - 384; int h = oo >> 6, d = oo & 63;
            const float* zc = z + (size_t)row * 256 * 64 + d;
            #pragma unroll 4
            for (int jj = 0; jj < 256; jj++) acc += al[h][jj] * zc[(size_t)jj * 64];
            fr[o] = acc;
        } else {
            int o3 = o - 1152; int h = o3 / 24;
            const ST* vb = VB + (size_t)b * 256 * BW + 384 + o3;
            #pragma unroll 4
            for (int jj = 0; jj < 256; jj++) acc += al[h][jj] * ldst(vb, (size_t)jj * BW);
            aggr[o3] = acc;
        }
    }
    __syncthreads();

    // ---- spatial feature epilogue ----
    if (tid < 96) {
        int t3 = tid * 3;
        float u0 = aggr[t3+0] - tv[0], u1 = aggr[t3+1] - tv[1], u2 = aggr[t3+2] - tv[2];
        float f0 = Rm[0]*u0 + Rm[3]*u1 + Rm[6]*u2;
        float f1 = Rm[1]*u0 + Rm[4]*u1 + Rm[7]*u2;
        float f2 = Rm[2]*u0 + Rm[5]*u1 + Rm[8]*u2;
        float fd = sqrtf(f0*f0 + f1*f1 + f2*f2);
        float inv = 1.f / (fd + 1e-4f);
        fr[1152 + t3 + 0] = f0; fr[1152 + t3 + 1] = f1; fr[1152 + t3 + 2] = f2;
        fr[1440 + tid] = fd;
        fr[1536 + t3 + 0] = f0*inv; fr[1536 + t3 + 1] = f1*inv; fr[1536 + t3 + 2] = f2*inv;
    }
    __syncthreads();

    // ---- Wo (split-K halves) + LN1 + MLP + LN2 ----
    int col = tid & 127, half = tid >> 7;
    float acc = 0.f;
    #pragma unroll 4
    for (int kk = half * 912; kk < half * 912 + 912; kk++)
        acc += fr[kk] * Wo[oWo + (size_t)kk * 128 + col];
    pacc[tid] = acc;
    __syncthreads();

    auto bsum = [&](float vv) -> float {
        for (int off = 32; off; off >>= 1) vv += __shfl_xor(vv, off, 64);
        if ((tid & 63) == 0) red2[tid >> 6] = vv;
        __syncthreads();
        float s = red2[0] + red2[1] + red2[2] + red2[3];
        __syncthreads();
        return s;
    };

    float val = x[(size_t)row * 128 + col] + bo[oB + col] + pacc[col] + pacc[128 + col];

    float mean = bsum(val) * (1.f / 256.f);
    float dv = val - mean;
    float var = bsum(dv * dv) * (1.f / 256.f);
    float xl = dv * rsqrtf(var + 1e-5f) * g1[oB + col] + b1ln[oB + col];
    shx[col] = xl;
    __syncthreads();

    float a1 = bb1[oB + col];
    #pragma unroll 4
    for (int kk = 0; kk < 128; kk++) a1 += shx[kk] * w1[oM + kk * 128 + col];
    a1 = fmaxf(a1, 0.f);
    __syncthreads();
    shx[col] = a1;
    __syncthreads();

    float a2 = bb2[oB + col];
    #pragma unroll 4
    for (int kk = 0; kk < 128; kk++) a2 += shx[kk] * w2[oM + kk * 128 + col];
    a2 = fmaxf(a2, 0.f);
    __syncthreads();
    shx[col] = a2;
    __syncthreads();

    float a3 = bb3[oB + col];
    #pragma unroll 4
    for (int kk = 0; kk < 128; kk++) a3 += shx[kk] * w3[oM + kk * 128 + col];
    float val2 = xl + a3;

    float mean2 = bsum(val2) * (1.f / 256.f);
    float dv2 = val2 - mean2;
    float var2 = bsum(dv2 * dv2) * (1.f / 256.f);
    if (tid < 128)
        x[(size_t)row * 128 + col] = dv2 * rsqrtf(var2 + 1e-5f) * g2[oB + col] + b2ln[oB + col];
}

// ---------- regression head (fp32 out) ----------
__global__ void k_final(const float* __restrict__ x, const float* __restrict__ Wreg,
                        const float* __restrict__ breg, float* __restrict__ out)
{
    int idx = blockIdx.x * 256 + threadIdx.x;   // 1024 outputs
    int b = idx >> 7, r = (idx >> 2) & 31, c = idx & 3;
    const float* xr = x + ((size_t)(b * 256 + 224 + r)) * 128;
    float acc = breg[c];
    for (int kk = 0; kk < 128; kk++) acc += xr[kk] * Wreg[kk * 4 + c];
    out[idx] = acc;
}

extern "C" void kernel_launch(void* const* d_in, const int* in_sizes, int n_in,
                              void* d_out, int out_size, void* d_ws, size_t ws_size,
                              hipStream_t stream)
{
    const float* rot  = (const float*)d_in[0];
    const float* pos  = (const float*)d_in[1];
    const float* resf = (const float*)d_in[2];
    const float* pair = (const float*)d_in[3];
    const float* Wq   = (const float*)d_in[5];
    const float* Wk   = (const float*)d_in[6];
    const float* Wv   = (const float*)d_in[7];
    const float* Wpb  = (const float*)d_in[8];
    const float* coef = (const float*)d_in[9];
    const float* Wqp  = (const float*)d_in[10];
    const float* Wkp  = (const float*)d_in[11];
    const float* Wvp  = (const float*)d_in[12];
    const float* Wo   = (const float*)d_in[13];
    const float* bo   = (const float*)d_in[14];
    const float* ln1g = (const float*)d_in[15];
    const float* ln1b = (const float*)d_in[16];
    const float* w1   = (const float*)d_in[17];
    const float* b1   = (const float*)d_in[18];
    const float* w2   = (const float*)d_in[19];
    const float* b2   = (const float*)d_in[20];
    const float* w3   = (const float*)d_in[21];
    const float* b3   = (const float*)d_in[22];
    const float* ln2g = (const float*)d_in[23];
    const float* ln2b = (const float*)d_in[24];
    const float* Wreg = (const float*)d_in[25];
    const float* breg = (const float*)d_in[26];

    float* X = (float*)d_ws;                       // BL*128 floats
    bool f32ws = ws_size >= (size_t)18 * 1024 * 1024;

    k_init<<<1024, 256, 0, stream>>>(resf, X);

    if (f32ws) {
        float* QB = X + (size_t)BL * 128;
        float* KB = QB + (size_t)BL * BW;
        float* VB = KB + (size_t)BL * BW;
        for (int l = 0; l < 6; l++) {
            k_proj<float><<<BL, 256, 0, stream>>>(X, Wq, Wk, Wv, Wqp, Wkp, Wvp,
                                                  rot, pos, QB, KB, VB, l);
            k_attn<float><<<BL, 256, 0, stream>>>(QB, KB, VB, pair, Wpb, coef, rot, pos, X,
                Wo, bo, ln1g, ln1b, w1, b1, w2, b2, w3, b3, ln2g, ln2b, l);
        }
    } else {
        bf16* QB = (bf16*)(X + (size_t)BL * 128);
        bf16* KB = QB + (size_t)BL * BW;
        bf16* VB = KB + (size_t)BL * BW;
        for (int l = 0; l < 6; l++) {
            k_proj<bf16><<<BL, 256, 0, stream>>>(X, Wq, Wk, Wv, Wqp, Wkp, Wvp,
                                                 rot, pos, QB, KB, VB, l);
            k_attn<bf16><<<BL, 256, 0, stream>>>(QB, KB, VB, pair, Wpb, coef, rot, pos, X,
                Wo, bo, ln1g, ln1b, w1, b1, w2, b2, w3, b3, ln2g, ln2b, l);
        }
    }

    k_final<<<4, 256, 0, stream>>>(X, Wreg, breg, (float*)d_out);
}